// Round 2
// baseline (331.775 us; speedup 1.0000x reference)
//
#include <hip/hip_runtime.h>
#include <hip/hip_bf16.h>

#define NROW 8192
#define NDIM 256
#define PANEL 1024
#define NPANEL (NROW / PANEL)
#define INV_T (1.0f / 0.07f)
#define K_BOT 819      // first selected descending rank
#define K_TOP 4095     // one past last selected rank
#define N_SEL 3276
#define N_UNSEL 4916   // 8192 - N_SEL (includes diagonal at -10)

typedef unsigned int u32;
typedef unsigned short u16;
typedef short s16;
typedef __bf16 bf16_t;
typedef s16 s16x8 __attribute__((ext_vector_type(8)));
typedef float f32x4 __attribute__((ext_vector_type(4)));

__device__ __forceinline__ u16 bfbits(float f) {
    return __builtin_bit_cast(u16, (bf16_t)f);   // RNE f32->bf16, raw bits
}
// order-preserving bf16-bits -> u16 key (bigger float <=> bigger key)
__device__ __forceinline__ u16 map16(u16 b) {
    return (b & 0x8000u) ? (u16)~b : (u16)(b | 0x8000u);
}
__device__ __forceinline__ float unmap16(u32 m) {
    u16 b = (m & 0x8000u) ? (u16)(m & 0x7FFFu) : (u16)~(u16)m;
    return __uint_as_float(((u32)b) << 16);
}

// ---------------- GEMM panel: keys = map16(bf16(Q @ K^T)) ----------------
// 128x128 tile, BK=32, 4 waves (2x2), wave = 64x64 via 4x4 frags of 16x16x32.
// fp32 inputs converted to bf16 inline during LDS staging.
__global__ __launch_bounds__(256) void gemm_keys(const float* __restrict__ Q,
                                                 const float* __restrict__ K,
                                                 u16* __restrict__ Cp,
                                                 int pbase) {
    constexpr int BK = 32;
    __shared__ __align__(16) char smem[128 * 132 * 2];   // 33792 B (union)
    s16* sA = (s16*)smem;                 // [128][32]
    s16* sB = (s16*)(smem + 128 * BK * 2);
    u16* sC = (u16*)smem;                 // [128][132] epilogue transpose

    const int tid  = threadIdx.x;
    const int lane = tid & 63;
    const int wid  = tid >> 6;
    const int wr = wid >> 1, wc = wid & 1;
    const int bm = blockIdx.y * 128;      // panel-local row base
    const int bn = blockIdx.x * 128;      // global col base

    const int kg = lane >> 4;
    const int fr = lane & 15;

    const int srow = tid >> 2;            // 0..63
    const int sj   = tid & 3;             // chunk 0..3 (8 bf16 each)
    const int sjp  = sj ^ ((srow >> 1) & 3);   // same swizzle for srow+64

    const float* qbase = Q + (size_t)(pbase + bm + srow) * NDIM + sj * 8;
    const float* kbase = K + (size_t)(bn + srow) * NDIM + sj * 8;

    f32x4 acc[4][4] = {};

    for (int k0 = 0; k0 < NDIM; k0 += BK) {
        __syncthreads();
#pragma unroll
        for (int s = 0; s < 2; ++s) {
            const float* qs = qbase + k0 + (size_t)(s * 64) * NDIM;
            float4 a0 = *(const float4*)qs;
            float4 a1 = *(const float4*)(qs + 4);
            s16x8 av;
            av[0] = (s16)bfbits(a0.x); av[1] = (s16)bfbits(a0.y);
            av[2] = (s16)bfbits(a0.z); av[3] = (s16)bfbits(a0.w);
            av[4] = (s16)bfbits(a1.x); av[5] = (s16)bfbits(a1.y);
            av[6] = (s16)bfbits(a1.z); av[7] = (s16)bfbits(a1.w);
            *(s16x8*)(&sA[(srow + s * 64) * BK + sjp * 8]) = av;

            const float* ks = kbase + k0 + (size_t)(s * 64) * NDIM;
            float4 b0 = *(const float4*)ks;
            float4 b1 = *(const float4*)(ks + 4);
            s16x8 bv;
            bv[0] = (s16)bfbits(b0.x); bv[1] = (s16)bfbits(b0.y);
            bv[2] = (s16)bfbits(b0.z); bv[3] = (s16)bfbits(b0.w);
            bv[4] = (s16)bfbits(b1.x); bv[5] = (s16)bfbits(b1.y);
            bv[6] = (s16)bfbits(b1.z); bv[7] = (s16)bfbits(b1.w);
            *(s16x8*)(&sB[(srow + s * 64) * BK + sjp * 8]) = bv;
        }
        __syncthreads();

        s16x8 af[4], bfv[4];
#pragma unroll
        for (int m = 0; m < 4; ++m) {
            int row = wr * 64 + m * 16 + fr;
            int jp = kg ^ ((row >> 1) & 3);
            af[m] = *(const s16x8*)(&sA[row * BK + jp * 8]);
        }
#pragma unroll
        for (int n = 0; n < 4; ++n) {
            int row = wc * 64 + n * 16 + fr;
            int jp = kg ^ ((row >> 1) & 3);
            bfv[n] = *(const s16x8*)(&sB[row * BK + jp * 8]);
        }
#pragma unroll
        for (int m = 0; m < 4; ++m)
#pragma unroll
            for (int n = 0; n < 4; ++n)
                acc[m][n] = __builtin_amdgcn_mfma_f32_16x16x32_bf16(
                    af[m], bfv[n], acc[m][n], 0, 0, 0);
    }

    __syncthreads();   // done reading sA/sB; reuse LDS as sC
#pragma unroll
    for (int m = 0; m < 4; ++m)
#pragma unroll
        for (int n = 0; n < 4; ++n)
#pragma unroll
            for (int jj = 0; jj < 4; ++jj) {
                int r = wr * 64 + m * 16 + kg * 4 + jj;   // C/D: row=kg*4+reg
                int c = wc * 64 + n * 16 + fr;            //      col=lane&15
                sC[r * 132 + c] = map16(bfbits(acc[m][n][jj]));
            }
    __syncthreads();
#pragma unroll
    for (int s = 0; s < 16; ++s) {
        int e = s * 1024 + tid * 4;
        int row = e >> 7, col = e & 127;
        *(ushort4*)(&Cp[(size_t)(bm + row) * NROW + bn + col]) =
            *(const ushort4*)(&sC[row * 132 + col]);
    }
}

// ---------------- per-row rank select + LSE on u16 keys ----------------
__device__ __forceinline__ void suffix_scan(const u32* hist, u32* scan, int t) {
    // scan[b] = sum_{d >= b} hist[d]; wave 0 does the work
    if (t < 64) {
        u32 h0 = hist[4 * t], h1 = hist[4 * t + 1];
        u32 h2 = hist[4 * t + 2], h3 = hist[4 * t + 3];
        u32 s3 = h3, s2 = h2 + s3, s1 = h1 + s2, s0 = h0 + s1;
        u32 incl = s0;
#pragma unroll
        for (int off = 1; off < 64; off <<= 1) {
            u32 v = __shfl_down(incl, off);
            if (t + off < 64) incl += v;
        }
        u32 excl = incl - s0;
        scan[4 * t]     = s0 + excl;
        scan[4 * t + 1] = s1 + excl;
        scan[4 * t + 2] = s2 + excl;
        scan[4 * t + 3] = s3 + excl;
    }
    __syncthreads();
}

__global__ __launch_bounds__(256) void rank_lse(const u16* __restrict__ Cp,
                                                const float* __restrict__ fq,
                                                const float* __restrict__ fk,
                                                float* __restrict__ loss,
                                                int pbase) {
    const int lrow = blockIdx.x;
    const int grow = pbase + lrow;
    const int t = threadIdx.x;
    __shared__ u16 su[NROW];          // 16 KB keys
    __shared__ u32 hist[256];
    __shared__ u32 scan[256];
    __shared__ u32 s_binA, s_remA, s_binB, s_remB;
    __shared__ float warr[4];
    __shared__ float wsum[4];
    __shared__ u32 wcnt[4][3];

    // load row keys (16B vector loads)
    const u16* rowp = Cp + (size_t)lrow * NROW;
#pragma unroll
    for (int i = 0; i < 4; ++i) {
        int c = i * 2048 + t * 8;
        *(uint4*)(&su[c]) = *(const uint4*)(rowp + c);
    }
    // exact fp32 l_pos
    float p = fq[(size_t)grow * NDIM + t] * fk[(size_t)grow * NDIM + t];
#pragma unroll
    for (int o = 32; o; o >>= 1) p += __shfl_down(p, o);
    if ((t & 63) == 0) warr[t >> 6] = p;
    __syncthreads();
    if (t == 0) su[grow] = 0;         // diagonal -> minimum sentinel
    const float lp = (warr[0] + warr[1]) + (warr[2] + warr[3]);
    __syncthreads();

    // ---- pass 1 (high byte, shared for both ranks) ----
    hist[t] = 0;
    __syncthreads();
#pragma unroll
    for (int i = 0; i < 32; ++i)
        atomicAdd(&hist[su[i * 256 + t] >> 8], 1u);
    __syncthreads();
    suffix_scan(hist, scan, t);
    {
        u32 above = (t < 255) ? scan[t + 1] : 0u;
        u32 h = hist[t];
        if ((u32)K_BOT >= above && (u32)K_BOT < above + h) { s_binA = (u32)t; s_remA = (u32)K_BOT - above; }
        u32 rb = (u32)(K_TOP - 1);
        if (rb >= above && rb < above + h) { s_binB = (u32)t; s_remB = rb - above; }
    }
    __syncthreads();
    const u32 hiA = s_binA, remA = s_remA;
    const u32 hiB = s_binB, remB = s_remB;
    const bool sameHi = (hiA == hiB);

    // ---- pass 2: low byte within bin hiA (and hiB if equal) ----
    hist[t] = 0;
    __syncthreads();
#pragma unroll
    for (int i = 0; i < 32; ++i) {
        u32 u = su[i * 256 + t];
        if ((u >> 8) == hiA) atomicAdd(&hist[u & 255u], 1u);
    }
    __syncthreads();
    suffix_scan(hist, scan, t);
    {
        u32 above = (t < 255) ? scan[t + 1] : 0u;
        u32 h = hist[t];
        if (remA >= above && remA < above + h) s_binA = (u32)t;
        if (sameHi && remB >= above && remB < above + h) s_binB = (u32)t;
    }
    __syncthreads();
    const u32 ua = (hiA << 8) | s_binA;
    u32 ub;
    if (sameHi) {
        ub = (hiB << 8) | s_binB;
    } else {
        // ---- pass 3: low byte within bin hiB ----
        hist[t] = 0;
        __syncthreads();
#pragma unroll
        for (int i = 0; i < 32; ++i) {
            u32 u = su[i * 256 + t];
            if ((u >> 8) == hiB) atomicAdd(&hist[u & 255u], 1u);
        }
        __syncthreads();
        suffix_scan(hist, scan, t);
        {
            u32 above = (t < 255) ? scan[t + 1] : 0u;
            u32 h = hist[t];
            if (remB >= above && remB < above + h) s_binB = (u32)t;
        }
        __syncthreads();
        ub = (hiB << 8) | s_binB;
    }

    // ---- final: tie-exact window sum + LSE ----
    const float a  = unmap16(ua);
    const float bv = unmap16(ub);
    const float m_ = fmaxf(fmaxf(lp, a), -10.0f) * INV_T;

    u32 cga = 0, cea = 0, cgb = 0;
    float sm = 0.f;
#pragma unroll
    for (int i = 0; i < 32; ++i) {
        u32 u = su[i * 256 + t];
        cga += (u > ua) ? 1u : 0u;
        cea += (u == ua) ? 1u : 0u;
        cgb += (u > ub) ? 1u : 0u;
        if (u < ua && u > ub) sm += __expf(unmap16(u) * INV_T - m_);
    }
#pragma unroll
    for (int o = 32; o; o >>= 1) {
        sm  += __shfl_down(sm, o);
        cga += __shfl_down(cga, o);
        cea += __shfl_down(cea, o);
        cgb += __shfl_down(cgb, o);
    }
    const int w = t >> 6;
    if ((t & 63) == 0) {
        wsum[w] = sm; wcnt[w][0] = cga; wcnt[w][1] = cea; wcnt[w][2] = cgb;
    }
    __syncthreads();
    if (t == 0) {
        float S = (wsum[0] + wsum[1]) + (wsum[2] + wsum[3]);
        u32 Ga = wcnt[0][0] + wcnt[1][0] + wcnt[2][0] + wcnt[3][0];
        u32 Ea = wcnt[0][1] + wcnt[1][1] + wcnt[2][1] + wcnt[3][1];
        u32 Gb = wcnt[0][2] + wcnt[1][2] + wcnt[2][2] + wcnt[3][2];
        float expA = __expf(a * INV_T - m_);
        float tot;
        if (ua == ub) {
            tot = (float)N_SEL * expA;
        } else {
            float expB = __expf(bv * INV_T - m_);
            tot = S + (float)(int)(Ga + Ea - (u32)K_BOT) * expA
                    + (float)(int)((u32)K_TOP - Gb) * expB;
        }
        tot += __expf(lp * INV_T - m_) + (float)N_UNSEL * __expf(-10.0f * INV_T - m_);
        loss[grow] = m_ + __logf(tot) - lp * INV_T;
    }
}

// ---------------- host ----------------
extern "C" void kernel_launch(void* const* d_in, const int* in_sizes, int n_in,
                              void* d_out, int out_size, void* d_ws, size_t ws_size,
                              hipStream_t stream) {
    const float* fq = (const float*)d_in[0];
    const float* fk = (const float*)d_in[1];
    float* out = (float*)d_out;
    u16* simP = (u16*)d_ws;   // PANEL * NROW * 2 = 16 MiB

    for (int pIdx = 0; pIdx < NPANEL; ++pIdx) {
        int pbase = pIdx * PANEL;
        gemm_keys<<<dim3(NROW / 128, PANEL / 128), 256, 0, stream>>>(fq, fk, simP, pbase);
        rank_lse<<<PANEL, 256, 0, stream>>>(simP, fq, fk, out, pbase);
    }
}

// Round 3
// 206.998 us; speedup vs baseline: 1.6028x; 1.6028x over previous
//
#include <hip/hip_runtime.h>
#include <hip/hip_bf16.h>

#define NROW 8192
#define NDIM 256
#define INV_T (1.0f / 0.07f)
#define K_BOT 819      // first selected descending rank
#define K_TOP 4095     // one past last selected rank
#define N_SEL 3276
#define N_UNSEL 4916   // 8192 - N_SEL (includes diagonal at -10)

typedef unsigned int u32;
typedef unsigned short u16;
typedef short s16;
typedef __bf16 bf16_t;
typedef s16 s16x8 __attribute__((ext_vector_type(8)));
typedef float f32x4 __attribute__((ext_vector_type(4)));

__device__ __forceinline__ u16 bfbits(float f) {
    return __builtin_bit_cast(u16, (bf16_t)f);   // RNE f32->bf16, raw bits
}
// order-preserving bf16-bits -> u16 key (bigger float <=> bigger key)
__device__ __forceinline__ u16 map16(u16 b) {
    return (b & 0x8000u) ? (u16)~b : (u16)(b | 0x8000u);
}
__device__ __forceinline__ float unmap16(u32 m) {
    u16 b = (m & 0x8000u) ? (u16)(m & 0x7FFFu) : (u16)~(u16)m;
    return __uint_as_float(((u32)b) << 16);
}

__device__ __forceinline__ void gload16(const void* g, void* l) {
    __builtin_amdgcn_global_load_lds(
        (const __attribute__((address_space(1))) u32*)g,
        (__attribute__((address_space(3))) u32*)l, 16, 0, 0);
}

// ---------------- fp32 -> bf16 ----------------
__global__ __launch_bounds__(256) void cvt_bf16(const float* __restrict__ in,
                                                u16* __restrict__ out) {
    int i = (blockIdx.x * 256 + threadIdx.x) * 4;
    float4 v = *(const float4*)(in + i);
    ushort4 o;
    o.x = bfbits(v.x); o.y = bfbits(v.y); o.z = bfbits(v.z); o.w = bfbits(v.w);
    *(ushort4*)(out + i) = o;
}

// ---------------- GEMM: keys = map16(bf16(Q @ K^T)) ----------------
// 128x128 tile, BK=64, 4 waves (2x2), wave = 64x64 via 4x4 frags of 16x16x32.
// Staging: global_load_lds dwordx4, linear LDS dest; chunk swizzle jp = j ^ (row&7)
// applied by pre-swizzling the per-lane GLOBAL source (rule #21) and un-applied
// on the ds_read side. K-loop is the 2-barrier m97 structure.
__global__ __launch_bounds__(256) void gemm_keys(const u16* __restrict__ Qb,
                                                 const u16* __restrict__ Kb,
                                                 u16* __restrict__ Cp) {
    constexpr int BK = 64;
    __shared__ __align__(16) char smem[128 * 132 * 2];   // 33792 B (union)
    u16* sA = (u16*)smem;                    // [128][64] bf16
    u16* sB = (u16*)(smem + 128 * BK * 2);   // [128][64]
    u16* sC = (u16*)smem;                    // [128][132] epilogue transpose

    const int tid  = threadIdx.x;
    const int lane = tid & 63;
    const int wid  = tid >> 6;
    const int wr = wid >> 1, wc = wid & 1;
    const int bm = blockIdx.y * 128;
    const int bn = blockIdx.x * 128;
    const int kg = lane >> 4;
    const int fr = lane & 15;

    // staging geometry: segment = 8 rows x 128B; lane l -> row seg*8 + (l>>3),
    // LDS chunk jp = l&7, which must hold source chunk j = jp ^ (row&7).
    const int srr = lane >> 3;                    // row within segment (= row&7)
    const int srj = (lane & 7) ^ srr;             // source chunk for this lane

    f32x4 acc[4][4] = {};

    for (int k0 = 0; k0 < NDIM; k0 += BK) {
        __syncthreads();
#pragma unroll
        for (int s = 0; s < 4; ++s) {
            int seg = wid * 4 + s;                // 0..15
            int row = seg * 8 + srr;
            gload16(Qb + (size_t)(bm + row) * NDIM + k0 + srj * 8, &sA[seg * 512]);
            gload16(Kb + (size_t)(bn + row) * NDIM + k0 + srj * 8, &sB[seg * 512]);
        }
        __syncthreads();                          // vmcnt(0) drain + barrier

#pragma unroll
        for (int kk = 0; kk < 2; ++kk) {
            s16x8 af[4], bfv[4];
#pragma unroll
            for (int m = 0; m < 4; ++m) {
                int row = wr * 64 + m * 16 + fr;
                int jp = (kk * 4 + kg) ^ (fr & 7);    // row&7 == fr&7 here
                af[m] = *(const s16x8*)(&sA[row * BK + jp * 8]);
            }
#pragma unroll
            for (int n = 0; n < 4; ++n) {
                int row = wc * 64 + n * 16 + fr;
                int jp = (kk * 4 + kg) ^ (fr & 7);
                bfv[n] = *(const s16x8*)(&sB[row * BK + jp * 8]);
            }
#pragma unroll
            for (int m = 0; m < 4; ++m)
#pragma unroll
                for (int n = 0; n < 4; ++n)
                    acc[m][n] = __builtin_amdgcn_mfma_f32_16x16x32_bf16(
                        af[m], bfv[n], acc[m][n], 0, 0, 0);
        }
    }

    __syncthreads();   // done reading sA/sB; reuse LDS as sC
#pragma unroll
    for (int m = 0; m < 4; ++m)
#pragma unroll
        for (int n = 0; n < 4; ++n)
#pragma unroll
            for (int jj = 0; jj < 4; ++jj) {
                int r = wr * 64 + m * 16 + kg * 4 + jj;   // C/D: row = (lane>>4)*4+reg
                int c = wc * 64 + n * 16 + fr;            //      col = lane&15
                sC[r * 132 + c] = map16(bfbits(acc[m][n][jj]));
            }
    __syncthreads();
#pragma unroll
    for (int it = 0; it < 8; ++it) {
        int c = it * 256 + tid;                   // 16B chunk index, 0..2047
        int row = c >> 4, col8 = (c & 15) * 8;
        *(uint4*)(&Cp[(size_t)(bm + row) * NROW + bn + col8]) =
            *(const uint4*)(&sC[row * 132 + col8]);
    }
}

// ---------------- per-row rank select + LSE on u16 keys ----------------
__device__ __forceinline__ void suffix_scan(const u32* hist, u32* scan, int t) {
    // scan[b] = sum_{d >= b} hist[d]; wave 0 does the work
    if (t < 64) {
        u32 h0 = hist[4 * t], h1 = hist[4 * t + 1];
        u32 h2 = hist[4 * t + 2], h3 = hist[4 * t + 3];
        u32 s3 = h3, s2 = h2 + s3, s1 = h1 + s2, s0 = h0 + s1;
        u32 incl = s0;
#pragma unroll
        for (int off = 1; off < 64; off <<= 1) {
            u32 v = __shfl_down(incl, off);
            if (t + off < 64) incl += v;
        }
        u32 excl = incl - s0;
        scan[4 * t]     = s0 + excl;
        scan[4 * t + 1] = s1 + excl;
        scan[4 * t + 2] = s2 + excl;
        scan[4 * t + 3] = s3 + excl;
    }
    __syncthreads();
}

__global__ __launch_bounds__(256) void rank_lse(const u16* __restrict__ Cp,
                                                const float* __restrict__ fq,
                                                const float* __restrict__ fk,
                                                float* __restrict__ loss) {
    const int row = blockIdx.x;
    const int t = threadIdx.x;
    __shared__ u16 su[NROW];          // 16 KB keys
    __shared__ u32 hist[256];
    __shared__ u32 scan[256];
    __shared__ u32 s_binA, s_remA, s_binB, s_remB;
    __shared__ float warr[4];
    __shared__ float wsum[4];
    __shared__ u32 wcnt[4][3];

    const u16* rowp = Cp + (size_t)row * NROW;
#pragma unroll
    for (int i = 0; i < 4; ++i) {
        int c = i * 2048 + t * 8;
        *(uint4*)(&su[c]) = *(const uint4*)(rowp + c);
    }
    // exact fp32 l_pos
    float p = fq[(size_t)row * NDIM + t] * fk[(size_t)row * NDIM + t];
#pragma unroll
    for (int o = 32; o; o >>= 1) p += __shfl_down(p, o);
    if ((t & 63) == 0) warr[t >> 6] = p;
    __syncthreads();
    if (t == 0) su[row] = 0;          // diagonal -> unique minimum sentinel
    const float lp = (warr[0] + warr[1]) + (warr[2] + warr[3]);
    __syncthreads();

    // ---- pass 1 (high byte, shared for both ranks) ----
    hist[t] = 0;
    __syncthreads();
#pragma unroll
    for (int i = 0; i < 32; ++i)
        atomicAdd(&hist[su[i * 256 + t] >> 8], 1u);
    __syncthreads();
    suffix_scan(hist, scan, t);
    {
        u32 above = (t < 255) ? scan[t + 1] : 0u;
        u32 h = hist[t];
        if ((u32)K_BOT >= above && (u32)K_BOT < above + h) { s_binA = (u32)t; s_remA = (u32)K_BOT - above; }
        u32 rb = (u32)(K_TOP - 1);
        if (rb >= above && rb < above + h) { s_binB = (u32)t; s_remB = rb - above; }
    }
    __syncthreads();
    const u32 hiA = s_binA, remA = s_remA;
    const u32 hiB = s_binB, remB = s_remB;
    const bool sameHi = (hiA == hiB);

    // ---- pass 2: low byte within bin hiA (and hiB if equal) ----
    hist[t] = 0;
    __syncthreads();
#pragma unroll
    for (int i = 0; i < 32; ++i) {
        u32 u = su[i * 256 + t];
        if ((u >> 8) == hiA) atomicAdd(&hist[u & 255u], 1u);
    }
    __syncthreads();
    suffix_scan(hist, scan, t);
    {
        u32 above = (t < 255) ? scan[t + 1] : 0u;
        u32 h = hist[t];
        if (remA >= above && remA < above + h) s_binA = (u32)t;
        if (sameHi && remB >= above && remB < above + h) s_binB = (u32)t;
    }
    __syncthreads();
    const u32 ua = (hiA << 8) | s_binA;
    u32 ub;
    if (sameHi) {
        ub = (hiB << 8) | s_binB;
    } else {
        // ---- pass 3: low byte within bin hiB ----
        hist[t] = 0;
        __syncthreads();
#pragma unroll
        for (int i = 0; i < 32; ++i) {
            u32 u = su[i * 256 + t];
            if ((u >> 8) == hiB) atomicAdd(&hist[u & 255u], 1u);
        }
        __syncthreads();
        suffix_scan(hist, scan, t);
        {
            u32 above = (t < 255) ? scan[t + 1] : 0u;
            u32 h = hist[t];
            if (remB >= above && remB < above + h) s_binB = (u32)t;
        }
        __syncthreads();
        ub = (hiB << 8) | s_binB;
    }

    // ---- final: tie-exact window sum + LSE ----
    const float a  = unmap16(ua);
    const float bv = unmap16(ub);
    const float m_ = fmaxf(fmaxf(lp, a), -10.0f) * INV_T;

    u32 cga = 0, cea = 0, cgb = 0;
    float sm = 0.f;
#pragma unroll
    for (int i = 0; i < 32; ++i) {
        u32 u = su[i * 256 + t];
        cga += (u > ua) ? 1u : 0u;
        cea += (u == ua) ? 1u : 0u;
        cgb += (u > ub) ? 1u : 0u;
        if (u < ua && u > ub) sm += __expf(unmap16(u) * INV_T - m_);
    }
#pragma unroll
    for (int o = 32; o; o >>= 1) {
        sm  += __shfl_down(sm, o);
        cga += __shfl_down(cga, o);
        cea += __shfl_down(cea, o);
        cgb += __shfl_down(cgb, o);
    }
    const int w = t >> 6;
    if ((t & 63) == 0) {
        wsum[w] = sm; wcnt[w][0] = cga; wcnt[w][1] = cea; wcnt[w][2] = cgb;
    }
    __syncthreads();
    if (t == 0) {
        float S = (wsum[0] + wsum[1]) + (wsum[2] + wsum[3]);
        u32 Ga = wcnt[0][0] + wcnt[1][0] + wcnt[2][0] + wcnt[3][0];
        u32 Ea = wcnt[0][1] + wcnt[1][1] + wcnt[2][1] + wcnt[3][1];
        u32 Gb = wcnt[0][2] + wcnt[1][2] + wcnt[2][2] + wcnt[3][2];
        float expA = __expf(a * INV_T - m_);
        float tot;
        if (ua == ub) {
            tot = (float)N_SEL * expA;
        } else {
            float expB = __expf(bv * INV_T - m_);
            tot = S + (float)(int)(Ga + Ea - (u32)K_BOT) * expA
                    + (float)(int)((u32)K_TOP - Gb) * expB;
        }
        tot += __expf(lp * INV_T - m_) + (float)N_UNSEL * __expf(-10.0f * INV_T - m_);
        loss[row] = m_ + __logf(tot) - lp * INV_T;
    }
}

// ---------------- host ----------------
extern "C" void kernel_launch(void* const* d_in, const int* in_sizes, int n_in,
                              void* d_out, int out_size, void* d_ws, size_t ws_size,
                              hipStream_t stream) {
    const float* fq = (const float*)d_in[0];
    const float* fk = (const float*)d_in[1];
    float* out = (float*)d_out;

    char* ws = (char*)d_ws;
    u16* keys = (u16*)ws;                                  // 128 MiB
    u16* qb = (u16*)(ws + (size_t)NROW * NROW * 2);        // 4 MiB
    u16* kb = qb + (size_t)NROW * NDIM;                    // 4 MiB

    cvt_bf16<<<2048, 256, 0, stream>>>(fq, qb);
    cvt_bf16<<<2048, 256, 0, stream>>>(fk, kb);
    gemm_keys<<<dim3(NROW / 128, NROW / 128), 256, 0, stream>>>(qb, kb, keys);
    rank_lse<<<NROW, 256, 0, stream>>>(keys, fq, fk, out);
}